// Round 8
// baseline (106.493 us; speedup 1.0000x reference)
//
#include <hip/hip_runtime.h>
#include <stdint.h>

// GCNConv forward on MI355X — aggregate-then-transform, bf16 MFMA, 6 launches.
//
//   out[t] = relu( ( dinv[t] * ( dinv[t]*x[t] + sum_{(s,t)} dinv[s]*x[s] ) ) @ W + b )
//
// Pipeline (fast path):
//   1. k_setup       : deg=0, pack W -> bf16 chunk-major Warr
//   2. k_count_xcast : deg histogram + slot[i]  ∥  xb = bf16(x)  (co-scheduled)
//   3. k_scan1       : chunk-local exclusive scan -> rowptr (local), + dinv;
//                      last block writes chunk-local rowptr[n]
//   4. k_scan2       : 1-block exclusive scan of 49 chunk totals -> coff
//   5. k_fill        : elist[rowptrL[d]+coff[d>>10]+slot[i]] = src[i] (no atomics)
//   6. k_gather_gemm : gather rows (predicated unroll-8, per-edge dinv fma) ->
//                      swizzled LDS tile -> MFMA vs W frags, nt-store out
//
// Lessons pinned: decoupled-lookback scan = 48 us (1 us/hop agent-atomic chain
// across 8 non-coherent XCD L2s) — keep two-pass scan. rocclr fillBuffer in
// top-5 is HARNESS POISON of d_ws, not ours. Gather is latency-bound: MLP
// (outstanding loads/wave) is the lever, not VALU.

#define FDIM 128
#define HDIM 128
#define SCAN_CHUNK 1024

using s8v   = __attribute__((ext_vector_type(8))) short;  // 8 bf16 = 4 VGPR
using f32x4 = __attribute__((ext_vector_type(4))) float;  // MFMA C/D

__device__ __forceinline__ unsigned bf16rn(float f) {
    unsigned u = __float_as_uint(f);
    return (u + 0x7fffu + ((u >> 16) & 1u)) >> 16;  // RNE
}
// lo += ds * bf16lo(w); hi += ds * bf16hi(w)
__device__ __forceinline__ void upfma(unsigned w, float ds, float& lo, float& hi) {
    lo = fmaf(ds, __uint_as_float(w << 16), lo);
    hi = fmaf(ds, __uint_as_float(w & 0xffff0000u), hi);
}

// ---------------- 1. setup: zero deg, pack Warr ----------------
__global__ __launch_bounds__(256) void k_setup(int* __restrict__ deg,
                                               const float* __restrict__ W,
                                               uint4* __restrict__ Warr,
                                               int n, int packW) {
    const int i = blockIdx.x * 256 + threadIdx.x;
    if (i < n) deg[i] = 0;
    if (packW && i < (FDIM / 8) * HDIM) {
        const int chunk = i >> 7, nn = i & 127;
        float v[8];
#pragma unroll
        for (int j = 0; j < 8; ++j) v[j] = W[(chunk * 8 + j) * HDIM + nn];
        uint4 o;
        o.x = bf16rn(v[0]) | (bf16rn(v[1]) << 16);
        o.y = bf16rn(v[2]) | (bf16rn(v[3]) << 16);
        o.z = bf16rn(v[4]) | (bf16rn(v[5]) << 16);
        o.w = bf16rn(v[6]) | (bf16rn(v[7]) << 16);
        Warr[i] = o;
    }
}

// ---------------- 2. histogram + slot ∥ bf16 cast ----------------
__global__ __launch_bounds__(256) void k_count_xcast(const int* __restrict__ dst,
                                                     int* __restrict__ deg,
                                                     int* __restrict__ slot,
                                                     const float* __restrict__ x,
                                                     uint4* __restrict__ xb,
                                                     int e, int n, int fillBlocks) {
    if ((int)blockIdx.x < fillBlocks) {
        const int i = blockIdx.x * 256 + threadIdx.x;
        if (i < e) slot[i] = atomicAdd(&deg[__builtin_nontemporal_load(dst + i)], 1);
    } else if (xb) {
        const long long idx = (long long)(blockIdx.x - fillBlocks) * 256 + threadIdx.x;
        if (idx >= (long long)n * (FDIM / 8)) return;
        const float4* xp = (const float4*)x + idx * 2;
        const float4 a = xp[0], b = xp[1];
        uint4 o;
        o.x = bf16rn(a.x) | (bf16rn(a.y) << 16);
        o.y = bf16rn(a.z) | (bf16rn(a.w) << 16);
        o.z = bf16rn(b.x) | (bf16rn(b.y) << 16);
        o.w = bf16rn(b.z) | (bf16rn(b.w) << 16);
        xb[idx] = o;
    }
}

// ---------------- 3. chunk-local scan + dinv ----------------
__global__ __launch_bounds__(256) void k_scan1(const int* __restrict__ deg,
                                               int* __restrict__ rowptr,
                                               int* __restrict__ partials,
                                               float* __restrict__ dinv, int n) {
    __shared__ int sdata[256];
    const int tid = threadIdx.x;
    const int base = blockIdx.x * SCAN_CHUNK + tid * 4;
    int v[4];
    int s = 0;
#pragma unroll
    for (int j = 0; j < 4; ++j) {
        int idx = base + j;
        v[j] = (idx < n) ? deg[idx] : 0;
        if (idx < n) dinv[idx] = rsqrtf((float)v[j] + 1.0f);  // +1 self-loop
        s += v[j];
    }
    sdata[tid] = s;
    __syncthreads();
    for (int off = 1; off < 256; off <<= 1) {
        int t = (tid >= off) ? sdata[tid - off] : 0;
        __syncthreads();
        sdata[tid] += t;
        __syncthreads();
    }
    int run = sdata[tid] - s;
#pragma unroll
    for (int j = 0; j < 4; ++j) {
        int idx = base + j;
        if (idx < n) rowptr[idx] = run;
        run += v[j];
    }
    if (tid == 255) {
        partials[blockIdx.x] = sdata[255];
        if (blockIdx.x == (int)gridDim.x - 1) rowptr[n] = sdata[255];  // chunk-local
    }
}

// ---------------- 4. exclusive scan of chunk totals (1 block) ----------------
__global__ __launch_bounds__(64) void k_scan2(int* __restrict__ partials, int nb) {
    int l = threadIdx.x;
    int v = (l < nb) ? partials[l] : 0;
    int inc = v;
    for (int off = 1; off < 64; off <<= 1) {
        int t = __shfl_up(inc, off);
        if (l >= off) inc += t;
    }
    if (l < nb) partials[l] = inc - v;  // becomes coff[]
}

// ---------------- 5. fill (no atomics) ----------------
__global__ __launch_bounds__(256) void k_fill(const int* __restrict__ src,
                                              const int* __restrict__ dst,
                                              const int* __restrict__ slot,
                                              const int* __restrict__ rowptr,
                                              const int* __restrict__ coff,
                                              int* __restrict__ elist, int e) {
    int i = blockIdx.x * 256 + threadIdx.x;
    if (i < e) {
        const int d = __builtin_nontemporal_load(dst + i);
        const int sl = __builtin_nontemporal_load(slot + i);
        elist[rowptr[d] + coff[d >> 10] + sl] = __builtin_nontemporal_load(src + i);
    }
}

// ---------------- 6. fused gather + MFMA GEMM ----------------
// Block = 256 thr (4 waves) = 16 nodes. Gather: 16 lanes/node, predicated
// unroll-8 (clamped pads = L1 hits), per-edge dinv fma, nt-loads on elist.
// W frags loaded AFTER the barrier (frees VGPRs during gather).
__global__ __launch_bounds__(256) void k_gather_gemm(
    const uint4* __restrict__ xb, const float* __restrict__ dinv,
    const int* __restrict__ rowptr, const int* __restrict__ coff,
    const int* __restrict__ elist, const uint4* __restrict__ Warr,
    const float* __restrict__ bias, float* __restrict__ out, int n) {
    __shared__ uint4 zlds[16][16];  // 4 KB
    const int tid = threadIdx.x;
    const int r = tid >> 4, q = tid & 15;
    const int node = blockIdx.x * 16 + r;
    const int wave = tid >> 6, lane = tid & 63;
    const int l16 = lane & 15, lg = lane >> 4;

    if (node < n) {
        const int co = coff[node >> 10];
        const int beg = rowptr[node] + co;
        // node+1 may cross into the next chunk:
        const int end = rowptr[node + 1] + coff[(node + 1) >> 10];
        const float di = dinv[node];

        const uint4* xq = xb + q;  // row stride = 16 uint4
        float a0 = 0.f, a1 = 0.f, a2 = 0.f, a3 = 0.f,
              a4 = 0.f, a5 = 0.f, a6 = 0.f, a7 = 0.f;
        {   // self term: di * x[t]
            const uint4 v = xq[(size_t)node * 16];
            upfma(v.x, di, a0, a1); upfma(v.y, di, a2, a3);
            upfma(v.z, di, a4, a5); upfma(v.w, di, a6, a7);
        }
        for (int j = beg; j < end; j += 8) {  // predicated unroll-8
            int sidx[8];
            float dw[8];
#pragma unroll
            for (int k = 0; k < 8; ++k) {
                const int jj = j + k;
                const int ii = (jj < end) ? jj : end - 1;
                sidx[k] = __builtin_nontemporal_load(elist + ii);
                dw[k] = (jj < end) ? dinv[sidx[k]] : 0.0f;
            }
            uint4 u[8];
#pragma unroll
            for (int k = 0; k < 8; ++k) u[k] = xq[(size_t)sidx[k] * 16];
#pragma unroll
            for (int k = 0; k < 8; ++k) {
                upfma(u[k].x, dw[k], a0, a1); upfma(u[k].y, dw[k], a2, a3);
                upfma(u[k].z, dw[k], a4, a5); upfma(u[k].w, dw[k], a6, a7);
            }
        }
        uint4 o;
        o.x = bf16rn(a0 * di) | (bf16rn(a1 * di) << 16);
        o.y = bf16rn(a2 * di) | (bf16rn(a3 * di) << 16);
        o.z = bf16rn(a4 * di) | (bf16rn(a5 * di) << 16);
        o.w = bf16rn(a6 * di) | (bf16rn(a7 * di) << 16);
        zlds[r][q ^ r] = o;
    }
    __syncthreads();

    // W fragments + bias (L2-hot, once per block) AFTER gather.
    s8v wf[2][4];
#pragma unroll
    for (int ntl = 0; ntl < 2; ++ntl)
#pragma unroll
        for (int ks = 0; ks < 4; ++ks)
            wf[ntl][ks] = *(const s8v*)&Warr[(ks * 4 + lg) * 128 +
                                             (wave * 2 + ntl) * 16 + l16];
    const float bv0 = bias[(wave * 2 + 0) * 16 + l16];
    const float bv1 = bias[(wave * 2 + 1) * 16 + l16];

    s8v afr[4];
#pragma unroll
    for (int ks = 0; ks < 4; ++ks)
        afr[ks] = *(const s8v*)&zlds[l16][(ks * 4 + lg) ^ l16];

#pragma unroll
    for (int ntl = 0; ntl < 2; ++ntl) {
        f32x4 acc = (f32x4){0.f, 0.f, 0.f, 0.f};
#pragma unroll
        for (int ks = 0; ks < 4; ++ks)
            acc = __builtin_amdgcn_mfma_f32_16x16x32_bf16(afr[ks], wf[ntl][ks], acc, 0, 0, 0);
        const int col = (wave * 2 + ntl) * 16 + l16;
        const float bv = ntl ? bv1 : bv0;
#pragma unroll
        for (int rr = 0; rr < 4; ++rr) {
            const int row = blockIdx.x * 16 + lg * 4 + rr;
            if (row < n)
                __builtin_nontemporal_store(fmaxf(acc[rr] + bv, 0.0f),
                                            &out[(size_t)row * HDIM + col]);
        }
    }
}

// ---------------- fallback path: fp32 ----------------
__global__ __launch_bounds__(256) void k_gather_f32(const float* __restrict__ x,
                                                    const float* __restrict__ dinv,
                                                    const int* __restrict__ rowptr,
                                                    const int* __restrict__ coff,
                                                    const int* __restrict__ elist,
                                                    float* __restrict__ z, int n) {
    const int lane = threadIdx.x & 31;
    const int node = blockIdx.x * 8 + (threadIdx.x >> 5);
    if (node >= n) return;
    const float di = dinv[node];
    float4 v = ((const float4*)(x + (size_t)node * FDIM))[lane];
    float4 sum;
    sum.x = di * v.x; sum.y = di * v.y; sum.z = di * v.z; sum.w = di * v.w;
    const int beg = rowptr[node] + coff[node >> 10];
    const int end = rowptr[node + 1] + coff[(node + 1) >> 10];
    for (int j = beg; j < end; ++j) {
        const int s = elist[j];
        const float ds = dinv[s];
        const float4 u = ((const float4*)(x + (size_t)s * FDIM))[lane];
        sum.x = fmaf(ds, u.x, sum.x);
        sum.y = fmaf(ds, u.y, sum.y);
        sum.z = fmaf(ds, u.z, sum.z);
        sum.w = fmaf(ds, u.w, sum.w);
    }
    float4 o;
    o.x = di * sum.x; o.y = di * sum.y; o.z = di * sum.z; o.w = di * sum.w;
    ((float4*)(z + (size_t)node * FDIM))[lane] = o;
}

__global__ __launch_bounds__(512) void k_gemm_relu(const float* __restrict__ W,
                                                   const float* __restrict__ bias,
                                                   float* __restrict__ zo, int n) {
    __shared__ float Wl[FDIM * HDIM];
    __shared__ float xs[4][FDIM];
    const int t = threadIdx.x;
    const int h = t & (HDIM - 1);
    const int g = t >> 7;
    {
        const float4* W4 = (const float4*)W;
        float4* Wl4 = (float4*)Wl;
        for (int i = t; i < FDIM * HDIM / 4; i += 512) Wl4[i] = W4[i];
    }
    __syncthreads();
    const float bv = bias[h];
    const int nq = (n + 3) >> 2;
    for (int q = blockIdx.x; q < nq; q += gridDim.x) {
        const int row = q * 4 + g;
        if (row < n) xs[g][h] = zo[(size_t)row * HDIM + h];
        __syncthreads();
        if (row < n) {
            float acc = bv;
#pragma unroll
            for (int k = 0; k < FDIM; ++k)
                acc = fmaf(xs[g][k], Wl[k * HDIM + h], acc);
            zo[(size_t)row * HDIM + h] = fmaxf(acc, 0.0f);
        }
        __syncthreads();
    }
}

extern "C" void kernel_launch(void* const* d_in, const int* in_sizes, int n_in,
                              void* d_out, int out_size, void* d_ws, size_t ws_size,
                              hipStream_t stream) {
    const float* x = (const float*)d_in[0];
    const float* W = (const float*)d_in[1];
    const float* b = (const float*)d_in[2];
    const int* ei = (const int*)d_in[3];
    float* out = (float*)d_out;

    const int H = in_sizes[2];      // 128
    const int F = in_sizes[1] / H;  // 128
    const int N = in_sizes[0] / F;  // 50000
    const int E = in_sizes[3] / 2;  // 600000
    const int* srcp = ei;
    const int* dstp = ei + E;

    auto align256 = [](size_t v) { return (v + 255) & ~(size_t)255; };
    char* ws = (char*)d_ws;
    size_t off = 0;
    int* deg = (int*)(ws + off);      off += align256((size_t)N * 4);
    float* dinv = (float*)(ws + off); off += align256((size_t)N * 4);
    int* rowptr = (int*)(ws + off);   off += align256((size_t)(N + 1) * 4);
    int* slot = (int*)(ws + off);     off += align256((size_t)E * 4);
    int* partials = (int*)(ws + off); off += 256;
    int* elist = (int*)(ws + off);    off += align256((size_t)E * 4);
    uint4* xb = (uint4*)(ws + off);   off += align256((size_t)N * FDIM * 2);
    uint4* Warr = (uint4*)(ws + off); off += align256((size_t)(FDIM / 8) * HDIM * 16);
    const bool fast = (ws_size >= off);

    const int nblk_scan = (N + SCAN_CHUNK - 1) / SCAN_CHUNK;  // 49
    const int fillBlocks = (E + 255) / 256;

    k_setup<<<(N + 255) / 256, 256, 0, stream>>>(deg, W, fast ? Warr : nullptr,
                                                 N, fast ? 1 : 0);
    if (fast) {
        const long long nchunks = (long long)N * (FDIM / 8);
        const int castBlocks = (int)((nchunks + 255) / 256);
        k_count_xcast<<<fillBlocks + castBlocks, 256, 0, stream>>>(
            dstp, deg, slot, x, xb, E, N, fillBlocks);
    } else {
        k_count_xcast<<<fillBlocks, 256, 0, stream>>>(dstp, deg, slot, x, nullptr,
                                                      E, N, fillBlocks);
    }
    k_scan1<<<nblk_scan, 256, 0, stream>>>(deg, rowptr, partials, dinv, N);
    k_scan2<<<1, 64, 0, stream>>>(partials, nblk_scan);
    k_fill<<<fillBlocks, 256, 0, stream>>>(srcp, dstp, slot, rowptr, partials, elist, E);
    if (fast) {
        k_gather_gemm<<<(N + 15) / 16, 256, 0, stream>>>(xb, dinv, rowptr, partials,
                                                         elist, Warr, b, out, N);
    } else {
        k_gather_f32<<<(N + 7) / 8, 256, 0, stream>>>(x, dinv, rowptr, partials,
                                                      elist, out, N);
        k_gemm_relu<<<512, 512, 0, stream>>>(W, b, out, N);
    }
}

// Round 9
// 84.948 us; speedup vs baseline: 1.2536x; 1.2536x over previous
//
#include <hip/hip_runtime.h>
#include <stdint.h>

// GCNConv forward on MI355X — aggregate-then-transform, bf16 MFMA, 6 launches.
//
//   out[t] = relu( ( dinv[t] * ( dinv[t]*x[t] + sum_{(s,t)} dinv[s]*x[s] ) ) @ W + b )
//
// Pipeline (fast path):
//   1. k_setup       : deg=0, pack W -> bf16 chunk-major Warr
//   2. k_count_xcast : deg histogram + slot[i]  ∥  xb = bf16(x)  (co-scheduled)
//   3. k_scan1       : chunk-local exclusive scan -> rowptr (local), + dinv;
//                      last block writes chunk-local rowptr[n]
//   4. k_scan2       : 1-block exclusive scan of 49 chunk totals -> coff
//   5. k_fill        : elist[rowptrL[d]+coff[d>>10]+slot[i]] = src[i] (no atomics)
//   6. k_gather_gemm : gather rows (unroll-4 + index prefetch pipeline,
//                      per-edge dinv fma) -> swizzled LDS tile -> MFMA, nt-store
//
// Lessons pinned:
//  - decoupled-lookback scan = 48 us (1 us/hop agent-atomic chain across 8
//    non-coherent XCD L2s) — keep two-pass scan.
//  - rocclr fillBuffer in top-5 is HARNESS POISON of d_ws, not ours.
//  - nt-hints ONLY on write-once streams. R8 put nontemporal_load on the
//    gather/fill index path: FETCH 68.6 MB (>> 15 MB compulsory), 48 us,
//    +18 us total. Caches must retain xb/elist.
//  - Gather is latency-bound: prefetch indices to overlap the dependent chain.

#define FDIM 128
#define HDIM 128
#define SCAN_CHUNK 1024

using s8v   = __attribute__((ext_vector_type(8))) short;  // 8 bf16 = 4 VGPR
using f32x4 = __attribute__((ext_vector_type(4))) float;  // MFMA C/D

__device__ __forceinline__ unsigned bf16rn(float f) {
    unsigned u = __float_as_uint(f);
    return (u + 0x7fffu + ((u >> 16) & 1u)) >> 16;  // RNE
}
// lo += ds * bf16lo(w); hi += ds * bf16hi(w)
__device__ __forceinline__ void upfma(unsigned w, float ds, float& lo, float& hi) {
    lo = fmaf(ds, __uint_as_float(w << 16), lo);
    hi = fmaf(ds, __uint_as_float(w & 0xffff0000u), hi);
}

// ---------------- 1. setup: zero deg, pack Warr ----------------
__global__ __launch_bounds__(256) void k_setup(int* __restrict__ deg,
                                               const float* __restrict__ W,
                                               uint4* __restrict__ Warr,
                                               int n, int packW) {
    const int i = blockIdx.x * 256 + threadIdx.x;
    if (i < n) deg[i] = 0;
    if (packW && i < (FDIM / 8) * HDIM) {
        const int chunk = i >> 7, nn = i & 127;
        float v[8];
#pragma unroll
        for (int j = 0; j < 8; ++j) v[j] = W[(chunk * 8 + j) * HDIM + nn];
        uint4 o;
        o.x = bf16rn(v[0]) | (bf16rn(v[1]) << 16);
        o.y = bf16rn(v[2]) | (bf16rn(v[3]) << 16);
        o.z = bf16rn(v[4]) | (bf16rn(v[5]) << 16);
        o.w = bf16rn(v[6]) | (bf16rn(v[7]) << 16);
        Warr[i] = o;
    }
}

// ---------------- 2. histogram + slot ∥ bf16 cast ----------------
__global__ __launch_bounds__(256) void k_count_xcast(const int* __restrict__ dst,
                                                     int* __restrict__ deg,
                                                     int* __restrict__ slot,
                                                     const float* __restrict__ x,
                                                     uint4* __restrict__ xb,
                                                     int e, int n, int fillBlocks) {
    if ((int)blockIdx.x < fillBlocks) {
        const int i = blockIdx.x * 256 + threadIdx.x;
        if (i < e) slot[i] = atomicAdd(&deg[dst[i]], 1);
    } else if (xb) {
        const long long idx = (long long)(blockIdx.x - fillBlocks) * 256 + threadIdx.x;
        if (idx >= (long long)n * (FDIM / 8)) return;
        const float4* xp = (const float4*)x + idx * 2;
        const float4 a = xp[0], b = xp[1];
        uint4 o;
        o.x = bf16rn(a.x) | (bf16rn(a.y) << 16);
        o.y = bf16rn(a.z) | (bf16rn(a.w) << 16);
        o.z = bf16rn(b.x) | (bf16rn(b.y) << 16);
        o.w = bf16rn(b.z) | (bf16rn(b.w) << 16);
        xb[idx] = o;
    }
}

// ---------------- 3. chunk-local scan + dinv ----------------
__global__ __launch_bounds__(256) void k_scan1(const int* __restrict__ deg,
                                               int* __restrict__ rowptr,
                                               int* __restrict__ partials,
                                               float* __restrict__ dinv, int n) {
    __shared__ int sdata[256];
    const int tid = threadIdx.x;
    const int base = blockIdx.x * SCAN_CHUNK + tid * 4;
    int v[4];
    int s = 0;
#pragma unroll
    for (int j = 0; j < 4; ++j) {
        int idx = base + j;
        v[j] = (idx < n) ? deg[idx] : 0;
        if (idx < n) dinv[idx] = rsqrtf((float)v[j] + 1.0f);  // +1 self-loop
        s += v[j];
    }
    sdata[tid] = s;
    __syncthreads();
    for (int off = 1; off < 256; off <<= 1) {
        int t = (tid >= off) ? sdata[tid - off] : 0;
        __syncthreads();
        sdata[tid] += t;
        __syncthreads();
    }
    int run = sdata[tid] - s;
#pragma unroll
    for (int j = 0; j < 4; ++j) {
        int idx = base + j;
        if (idx < n) rowptr[idx] = run;
        run += v[j];
    }
    if (tid == 255) {
        partials[blockIdx.x] = sdata[255];
        if (blockIdx.x == (int)gridDim.x - 1) rowptr[n] = sdata[255];  // chunk-local
    }
}

// ---------------- 4. exclusive scan of chunk totals (1 block) ----------------
__global__ __launch_bounds__(64) void k_scan2(int* __restrict__ partials, int nb) {
    int l = threadIdx.x;
    int v = (l < nb) ? partials[l] : 0;
    int inc = v;
    for (int off = 1; off < 64; off <<= 1) {
        int t = __shfl_up(inc, off);
        if (l >= off) inc += t;
    }
    if (l < nb) partials[l] = inc - v;  // becomes coff[]
}

// ---------------- 5. fill (no atomics) ----------------
__global__ __launch_bounds__(256) void k_fill(const int* __restrict__ src,
                                              const int* __restrict__ dst,
                                              const int* __restrict__ slot,
                                              const int* __restrict__ rowptr,
                                              const int* __restrict__ coff,
                                              int* __restrict__ elist, int e) {
    int i = blockIdx.x * 256 + threadIdx.x;
    if (i < e) {
        const int d = dst[i];
        elist[rowptr[d] + coff[d >> 10] + slot[i]] = src[i];
    }
}

// ---------------- 6. fused gather + MFMA GEMM ----------------
// Block = 256 thr (4 waves) = 16 nodes. Gather: 16 lanes/node, unroll-4 with
// one-stage index prefetch (elist loads for iter i+1 issue before the
// dependent dinv/row loads of iter i). W frags preloaded early (overlap).
__global__ __launch_bounds__(256) void k_gather_gemm(
    const uint4* __restrict__ xb, const float* __restrict__ dinv,
    const int* __restrict__ rowptr, const int* __restrict__ coff,
    const int* __restrict__ elist, const uint4* __restrict__ Warr,
    const float* __restrict__ bias, float* __restrict__ out, int n) {
    __shared__ uint4 zlds[16][16];  // 4 KB
    const int tid = threadIdx.x;
    const int r = tid >> 4, q = tid & 15;
    const int node = blockIdx.x * 16 + r;
    const int wave = tid >> 6, lane = tid & 63;
    const int l16 = lane & 15, lg = lane >> 4;

    // Early: row bounds + dinv (issue before W preload to hide latency).
    int beg = 0, end = 0;
    float di = 0.0f;
    if (node < n) {
        beg = rowptr[node] + coff[node >> 10];
        end = rowptr[node + 1] + coff[(node + 1) >> 10];  // may cross chunk
        di = dinv[node];
    }

    // Preload W fragments (L2-hot) + bias; overlaps with gather chain.
    s8v wf[2][4];
#pragma unroll
    for (int ntl = 0; ntl < 2; ++ntl)
#pragma unroll
        for (int ks = 0; ks < 4; ++ks)
            wf[ntl][ks] = *(const s8v*)&Warr[(ks * 4 + lg) * 128 +
                                             (wave * 2 + ntl) * 16 + l16];
    const float bv0 = bias[(wave * 2 + 0) * 16 + l16];
    const float bv1 = bias[(wave * 2 + 1) * 16 + l16];

    if (node < n) {
        const uint4* xq = xb + q;  // row stride = 16 uint4
        float a0 = 0.f, a1 = 0.f, a2 = 0.f, a3 = 0.f,
              a4 = 0.f, a5 = 0.f, a6 = 0.f, a7 = 0.f;
        {   // self term: di * x[t]
            const uint4 v = xq[(size_t)node * 16];
            upfma(v.x, di, a0, a1); upfma(v.y, di, a2, a3);
            upfma(v.z, di, a4, a5); upfma(v.w, di, a6, a7);
        }
        if (beg < end) {
            const int last = end - 1;
            int sidx[4];
#pragma unroll
            for (int k = 0; k < 4; ++k) {
                const int jj = beg + k;
                sidx[k] = elist[jj < end ? jj : last];
            }
            for (int j = beg; j < end; j += 4) {
                int snext[4];
#pragma unroll
                for (int k = 0; k < 4; ++k) {   // prefetch next iteration's indices
                    const int jj = j + 4 + k;
                    snext[k] = elist[jj < end ? jj : last];
                }
                float dw[4];
                uint4 u[4];
#pragma unroll
                for (int k = 0; k < 4; ++k) {   // dinv + row loads issue together
                    dw[k] = (j + k < end) ? dinv[sidx[k]] : 0.0f;
                    u[k] = xq[(size_t)sidx[k] * 16];
                }
#pragma unroll
                for (int k = 0; k < 4; ++k) {
                    upfma(u[k].x, dw[k], a0, a1); upfma(u[k].y, dw[k], a2, a3);
                    upfma(u[k].z, dw[k], a4, a5); upfma(u[k].w, dw[k], a6, a7);
                }
#pragma unroll
                for (int k = 0; k < 4; ++k) sidx[k] = snext[k];
            }
        }
        uint4 o;
        o.x = bf16rn(a0 * di) | (bf16rn(a1 * di) << 16);
        o.y = bf16rn(a2 * di) | (bf16rn(a3 * di) << 16);
        o.z = bf16rn(a4 * di) | (bf16rn(a5 * di) << 16);
        o.w = bf16rn(a6 * di) | (bf16rn(a7 * di) << 16);
        zlds[r][q ^ r] = o;
    }
    __syncthreads();

    s8v afr[4];
#pragma unroll
    for (int ks = 0; ks < 4; ++ks)
        afr[ks] = *(const s8v*)&zlds[l16][(ks * 4 + lg) ^ l16];

#pragma unroll
    for (int ntl = 0; ntl < 2; ++ntl) {
        f32x4 acc = (f32x4){0.f, 0.f, 0.f, 0.f};
#pragma unroll
        for (int ks = 0; ks < 4; ++ks)
            acc = __builtin_amdgcn_mfma_f32_16x16x32_bf16(afr[ks], wf[ntl][ks], acc, 0, 0, 0);
        const int col = (wave * 2 + ntl) * 16 + l16;
        const float bv = ntl ? bv1 : bv0;
#pragma unroll
        for (int rr = 0; rr < 4; ++rr) {
            const int row = blockIdx.x * 16 + lg * 4 + rr;
            if (row < n)
                __builtin_nontemporal_store(fmaxf(acc[rr] + bv, 0.0f),
                                            &out[(size_t)row * HDIM + col]);
        }
    }
}

// ---------------- fallback path: fp32 ----------------
__global__ __launch_bounds__(256) void k_gather_f32(const float* __restrict__ x,
                                                    const float* __restrict__ dinv,
                                                    const int* __restrict__ rowptr,
                                                    const int* __restrict__ coff,
                                                    const int* __restrict__ elist,
                                                    float* __restrict__ z, int n) {
    const int lane = threadIdx.x & 31;
    const int node = blockIdx.x * 8 + (threadIdx.x >> 5);
    if (node >= n) return;
    const float di = dinv[node];
    float4 v = ((const float4*)(x + (size_t)node * FDIM))[lane];
    float4 sum;
    sum.x = di * v.x; sum.y = di * v.y; sum.z = di * v.z; sum.w = di * v.w;
    const int beg = rowptr[node] + coff[node >> 10];
    const int end = rowptr[node + 1] + coff[(node + 1) >> 10];
    for (int j = beg; j < end; ++j) {
        const int s = elist[j];
        const float ds = dinv[s];
        const float4 u = ((const float4*)(x + (size_t)s * FDIM))[lane];
        sum.x = fmaf(ds, u.x, sum.x);
        sum.y = fmaf(ds, u.y, sum.y);
        sum.z = fmaf(ds, u.z, sum.z);
        sum.w = fmaf(ds, u.w, sum.w);
    }
    float4 o;
    o.x = di * sum.x; o.y = di * sum.y; o.z = di * sum.z; o.w = di * sum.w;
    ((float4*)(z + (size_t)node * FDIM))[lane] = o;
}

__global__ __launch_bounds__(512) void k_gemm_relu(const float* __restrict__ W,
                                                   const float* __restrict__ bias,
                                                   float* __restrict__ zo, int n) {
    __shared__ float Wl[FDIM * HDIM];
    __shared__ float xs[4][FDIM];
    const int t = threadIdx.x;
    const int h = t & (HDIM - 1);
    const int g = t >> 7;
    {
        const float4* W4 = (const float4*)W;
        float4* Wl4 = (float4*)Wl;
        for (int i = t; i < FDIM * HDIM / 4; i += 512) Wl4[i] = W4[i];
    }
    __syncthreads();
    const float bv = bias[h];
    const int nq = (n + 3) >> 2;
    for (int q = blockIdx.x; q < nq; q += gridDim.x) {
        const int row = q * 4 + g;
        if (row < n) xs[g][h] = zo[(size_t)row * HDIM + h];
        __syncthreads();
        if (row < n) {
            float acc = bv;
#pragma unroll
            for (int k = 0; k < FDIM; ++k)
                acc = fmaf(xs[g][k], Wl[k * HDIM + h], acc);
            zo[(size_t)row * HDIM + h] = fmaxf(acc, 0.0f);
        }
        __syncthreads();
    }
}

extern "C" void kernel_launch(void* const* d_in, const int* in_sizes, int n_in,
                              void* d_out, int out_size, void* d_ws, size_t ws_size,
                              hipStream_t stream) {
    const float* x = (const float*)d_in[0];
    const float* W = (const float*)d_in[1];
    const float* b = (const float*)d_in[2];
    const int* ei = (const int*)d_in[3];
    float* out = (float*)d_out;

    const int H = in_sizes[2];      // 128
    const int F = in_sizes[1] / H;  // 128
    const int N = in_sizes[0] / F;  // 50000
    const int E = in_sizes[3] / 2;  // 600000
    const int* srcp = ei;
    const int* dstp = ei + E;

    auto align256 = [](size_t v) { return (v + 255) & ~(size_t)255; };
    char* ws = (char*)d_ws;
    size_t off = 0;
    int* deg = (int*)(ws + off);      off += align256((size_t)N * 4);
    float* dinv = (float*)(ws + off); off += align256((size_t)N * 4);
    int* rowptr = (int*)(ws + off);   off += align256((size_t)(N + 1) * 4);
    int* slot = (int*)(ws + off);     off += align256((size_t)E * 4);
    int* partials = (int*)(ws + off); off += 256;
    int* elist = (int*)(ws + off);    off += align256((size_t)E * 4);
    uint4* xb = (uint4*)(ws + off);   off += align256((size_t)N * FDIM * 2);
    uint4* Warr = (uint4*)(ws + off); off += align256((size_t)(FDIM / 8) * HDIM * 16);
    const bool fast = (ws_size >= off);

    const int nblk_scan = (N + SCAN_CHUNK - 1) / SCAN_CHUNK;  // 49
    const int fillBlocks = (E + 255) / 256;

    k_setup<<<(N + 255) / 256, 256, 0, stream>>>(deg, W, fast ? Warr : nullptr,
                                                 N, fast ? 1 : 0);
    if (fast) {
        const long long nchunks = (long long)N * (FDIM / 8);
        const int castBlocks = (int)((nchunks + 255) / 256);
        k_count_xcast<<<fillBlocks + castBlocks, 256, 0, stream>>>(
            dstp, deg, slot, x, xb, E, N, fillBlocks);
    } else {
        k_count_xcast<<<fillBlocks, 256, 0, stream>>>(dstp, deg, slot, x, nullptr,
                                                      E, N, fillBlocks);
    }
    k_scan1<<<nblk_scan, 256, 0, stream>>>(deg, rowptr, partials, dinv, N);
    k_scan2<<<1, 64, 0, stream>>>(partials, nblk_scan);
    k_fill<<<fillBlocks, 256, 0, stream>>>(srcp, dstp, slot, rowptr, partials, elist, E);
    if (fast) {
        k_gather_gemm<<<(N + 15) / 16, 256, 0, stream>>>(xb, dinv, rowptr, partials,
                                                         elist, Warr, b, out, N);
    } else {
        k_gather_f32<<<(N + 7) / 8, 256, 0, stream>>>(x, dinv, rowptr, partials,
                                                      elist, out, N);
        k_gemm_relu<<<512, 512, 0, stream>>>(W, b, out, N);
    }
}